// Round 9
// baseline (168.734 us; speedup 1.0000x reference)
//
#include <hip/hip_runtime.h>
#include <math.h>

// Problem constants (fixed by setup_inputs)
#define N_TOTAL 2097152
#define NT 512              // threads per block (8 waves)
#define NC 8                // elements per thread
#define EPB (NT * NC)       // 4096 elements per block
#define NB (N_TOTAL / EPB)  // 512 blocks
#define NWAVE (NT / 64)     // 8 waves per block
#define NWORD (NB / 32)     // 16 bitset words for ready flags

// Projective map on homogeneous (x, g, 1):
//   x' = (al*x + be) / (ga*x + de)
//   g' = (e*x + c*g + f) / (ga*x + de)
// Matrix [[al,0,be],[e,c,f],[ga,0,de]] — closed under composition.
// Compose algebra in DOUBLE; per-element decay P in fp32 (matches the fp32
// reference: fp32 diff of adjacent sorted t is exact, expf ~1 ulp).
struct DMat { double al, be, ga, de, c, e, f; };

__device__ __forceinline__ DMat dmat_identity() {
    DMat m; m.al = 1.0; m.be = 0.0; m.ga = 0.0; m.de = 1.0; m.c = 1.0; m.e = 0.0; m.f = 0.0;
    return m;
}

// A applied AFTER B (matrix product A*B)
__device__ __forceinline__ DMat dmat_compose(const DMat& A, const DMat& B) {
    DMat r;
    r.al = A.al * B.al + A.be * B.ga;
    r.be = A.al * B.be + A.be * B.de;
    r.ga = A.ga * B.al + A.de * B.ga;
    r.de = A.ga * B.be + A.de * B.de;
    r.c  = A.c * B.c;
    r.e  = A.e * B.al + A.c * B.e + A.f * B.ga;
    r.f  = A.e * B.be + A.c * B.f + A.f * B.de;
    return r;
}

// Scale-invariant normalization; guarded so it can never manufacture NaN/Inf.
__device__ __forceinline__ void dmat_normalize(DMat& m) {
    double mx = fmax(fabs(m.al), fabs(m.be));
    mx = fmax(mx, fabs(m.ga));
    mx = fmax(mx, fabs(m.de));
    mx = fmax(mx, fabs(m.c));
    mx = fmax(mx, fabs(m.e));
    mx = fmax(mx, fabs(m.f));
    if (!(mx > 0.0) || isinf(mx)) return;   // all-zero or corrupt: leave as-is
    double inv = 1.0 / mx;
    m.al *= inv; m.be *= inv; m.ga *= inv; m.de *= inv;
    m.c *= inv; m.e *= inv; m.f *= inv;
}

__device__ __forceinline__ DMat dmat_shfl_up(const DMat& m, int d) {
    DMat r;
    r.al = __shfl_up(m.al, d); r.be = __shfl_up(m.be, d);
    r.ga = __shfl_up(m.ga, d); r.de = __shfl_up(m.de, d);
    r.c  = __shfl_up(m.c,  d); r.e  = __shfl_up(m.e,  d);
    r.f  = __shfl_up(m.f,  d);
    return r;
}

__device__ __forceinline__ DMat dmat_shfl_bcast(const DMat& m, int src) {
    DMat r;
    r.al = __shfl(m.al, src); r.be = __shfl(m.be, src);
    r.ga = __shfl(m.ga, src); r.de = __shfl(m.de, src);
    r.c  = __shfl(m.c,  src); r.e  = __shfl(m.e,  src);
    r.f  = __shfl(m.f,  src);
    return r;
}

// Barrier-free inclusive scan across the 64 lanes of a wave.
__device__ __forceinline__ DMat dmat_wave_scan64(DMat mine, int lane) {
    #pragma unroll
    for (int d = 1; d < 64; d <<= 1) {
        DMat o = dmat_shfl_up(mine, d);
        if (lane >= d) mine = dmat_compose(mine, o);
    }
    return mine;
}

__device__ __forceinline__ DMat elem_mat(double P, double a, double U, double V, double yy) {
    double p = P * P;
    DMat m;
    m.al = p * (a - 2.0 * U * V);
    m.be = V * V;
    m.ga = -(p * U * U);
    m.de = a;
    m.c  = P * (a - U * V);
    m.e  = -(yy * p * U);
    m.f  = yy * V;
    return m;
}

// Register-resident 4-way select (avoid runtime-indexed array -> scratch).
__device__ __forceinline__ double band_amp(int b, double a1, double a2, double a3) {
    double lo = (b & 1) ? a1 : 1.0;
    double hi = (b & 1) ? a3 : a2;
    return (b & 2) ? hi : lo;
}

// Device-coherent (agent-scope) matrix store/load for cross-block handoff.
__device__ __forceinline__ void dmat_store_agent(double* p, const DMat& m) {
    __hip_atomic_store(&p[0], m.al, __ATOMIC_RELAXED, __HIP_MEMORY_SCOPE_AGENT);
    __hip_atomic_store(&p[1], m.be, __ATOMIC_RELAXED, __HIP_MEMORY_SCOPE_AGENT);
    __hip_atomic_store(&p[2], m.ga, __ATOMIC_RELAXED, __HIP_MEMORY_SCOPE_AGENT);
    __hip_atomic_store(&p[3], m.de, __ATOMIC_RELAXED, __HIP_MEMORY_SCOPE_AGENT);
    __hip_atomic_store(&p[4], m.c,  __ATOMIC_RELAXED, __HIP_MEMORY_SCOPE_AGENT);
    __hip_atomic_store(&p[5], m.e,  __ATOMIC_RELAXED, __HIP_MEMORY_SCOPE_AGENT);
    __hip_atomic_store(&p[6], m.f,  __ATOMIC_RELAXED, __HIP_MEMORY_SCOPE_AGENT);
}

__device__ __forceinline__ DMat dmat_load_agent(const double* p) {
    DMat m;
    m.al = __hip_atomic_load(&p[0], __ATOMIC_RELAXED, __HIP_MEMORY_SCOPE_AGENT);
    m.be = __hip_atomic_load(&p[1], __ATOMIC_RELAXED, __HIP_MEMORY_SCOPE_AGENT);
    m.ga = __hip_atomic_load(&p[2], __ATOMIC_RELAXED, __HIP_MEMORY_SCOPE_AGENT);
    m.de = __hip_atomic_load(&p[3], __ATOMIC_RELAXED, __HIP_MEMORY_SCOPE_AGENT);
    m.c  = __hip_atomic_load(&p[4], __ATOMIC_RELAXED, __HIP_MEMORY_SCOPE_AGENT);
    m.e  = __hip_atomic_load(&p[5], __ATOMIC_RELAXED, __HIP_MEMORY_SCOPE_AGENT);
    m.f  = __hip_atomic_load(&p[6], __ATOMIC_RELAXED, __HIP_MEMORY_SCOPE_AGENT);
    return m;
}

// ------------------------- single fused kernel ---------------------------
// Ticket-ordered decoupled lookback (deadlock-free at ANY occupancy; proven
// correct in round 8) with round-8's two measured pathologies fixed:
//  - ready flags are a 512-bit BITSET (16 u32): publish = 1 atomicOr;
//    ONLY lanes 0..15 of wave 0 spin (16 spinners/block, was ~256/block)
//  - NO spI LDS table: Eb needs only the ordered product of L[0..bid-1];
//    identity-pad >= bid, 8-wave shuffle scan, 8 wave totals in 448 B LDS,
//    then 7 serial composes per thread. LDS 30 KB -> <1 KB.
__global__ __launch_bounds__(NT, 2) void k_fused(
    const float* __restrict__ t, const int* __restrict__ band,
    const float* __restrict__ y, const float* __restrict__ yerr,
    const float* __restrict__ lad, const float* __restrict__ lkp,
    double* __restrict__ L, double* __restrict__ accum,
    unsigned int* __restrict__ ticket, unsigned int* __restrict__ done,
    unsigned int* __restrict__ words, float* __restrict__ out)
{
    __shared__ double totW[7 * NWAVE];   // wave totals (phase 1, reused in spine)
    __shared__ double red[2 * NWAVE];
    __shared__ unsigned int s_vbid;

    const int tid  = threadIdx.x;
    const int lane = tid & 63;
    const int wid  = tid >> 6;

    // ---- ticket: logical block id in actual start order ----
    if (tid == 0) s_vbid = atomicAdd(ticket, 1u);
    __syncthreads();
    const int bid = (int)s_vbid;

    const double sigma2 = exp(2.0 * (double)lkp[0]);
    const float inv_ell_f = expf(-lkp[1]);
    const double amp1 = exp((double)lad[0]);
    const double amp2 = exp((double)lad[1]);
    const double amp3 = exp((double)lad[2]);

    const int gid  = bid * NT + tid;
    const int base = gid * NC;
    const bool first = (gid == 0);

    // ---- loads (all issued up front) ----
    float4 tvA = *reinterpret_cast<const float4*>(t + base);
    float4 tvB = *reinterpret_cast<const float4*>(t + base + 4);
    float4 yvA = *reinterpret_cast<const float4*>(y + base);
    float4 yvB = *reinterpret_cast<const float4*>(y + base + 4);
    float4 evA = *reinterpret_cast<const float4*>(yerr + base);
    float4 evB = *reinterpret_cast<const float4*>(yerr + base + 4);
    int4   bvA = *reinterpret_cast<const int4*>(band + base);
    int4   bvB = *reinterpret_cast<const int4*>(band + base + 4);
    float tpA = first ? 0.0f : t[base - 1];
    float tpB = tvA.w;                       // t[base+3], already loaded

    float tA[4] = {tvA.x, tvA.y, tvA.z, tvA.w};
    float yA[4] = {yvA.x, yvA.y, yvA.z, yvA.w};
    float eA[4] = {evA.x, evA.y, evA.z, evA.w};
    int   bA[4] = {bvA.x, bvA.y, bvA.z, bvA.w};
    float tB[4] = {tvB.x, tvB.y, tvB.z, tvB.w};
    float yB[4] = {yvB.x, yvB.y, yvB.z, yvB.w};
    float eB[4] = {evB.x, evB.y, evB.z, evB.w};
    int   bB[4] = {bvB.x, bvB.y, bvB.z, bvB.w};

    // replay state: 3x8 fp32 + 1 packed-band u32 = 25 VGPRs
    float Pv[NC], av[NC], yvv[NC];
    unsigned int bpack = 0;

    // ---- phase 1: two independent 4-element chains (2x ILP) ----
    DMat accA = dmat_identity();
    DMat accB = dmat_identity();
    #pragma unroll
    for (int j = 0; j < 4; ++j) {
        {   // chain A: elements [0, 4)
            int b = bA[j] & 3;
            bpack |= (unsigned int)b << (2 * j);
            double u = band_amp(b, amp1, amp2, amp3);
            double U = sigma2 * u;
            double a = (double)eA[j] * (double)eA[j] + U * u;
            float dt = tA[j] - tpA; tpA = tA[j];
            float pf = (first && j == 0) ? 0.0f : expf(-dt * inv_ell_f);
            Pv[j] = pf; av[j] = (float)a; yvv[j] = yA[j];
            accA = dmat_compose(elem_mat((double)pf, a, U, u, (double)yA[j]), accA);
        }
        {   // chain B: elements [4, 8) — independent of chain A
            int ix = 4 + j;
            int b = bB[j] & 3;
            bpack |= (unsigned int)b << (2 * ix);
            double u = band_amp(b, amp1, amp2, amp3);
            double U = sigma2 * u;
            double a = (double)eB[j] * (double)eB[j] + U * u;
            float dt = tB[j] - tpB; tpB = tB[j];
            float pf = expf(-dt * inv_ell_f);
            Pv[ix] = pf; av[ix] = (float)a; yvv[ix] = yB[j];
            accB = dmat_compose(elem_mat((double)pf, a, U, u, (double)yB[j]), accB);
        }
    }
    DMat acc = dmat_compose(accB, accA);
    dmat_normalize(acc);

    // ---- barrier-free wave scan; 1 LDS step for the 8 wave totals ----
    DMat incl = dmat_wave_scan64(acc, lane);
    dmat_normalize(incl);
    DMat laneExcl = dmat_shfl_up(incl, 1);   // lane 0: garbage (handled below)
    if (lane == 63) {                        // publish wave total
        totW[0 * NWAVE + wid] = incl.al; totW[1 * NWAVE + wid] = incl.be;
        totW[2 * NWAVE + wid] = incl.ga; totW[3 * NWAVE + wid] = incl.de;
        totW[4 * NWAVE + wid] = incl.c;  totW[5 * NWAVE + wid] = incl.e;
        totW[6 * NWAVE + wid] = incl.f;
    }
    __syncthreads();

    // redundant 8-element shuffle scan of wave totals (every wave; no barrier)
    DMat tv = dmat_identity();
    if (lane < NWAVE) {
        tv.al = totW[0 * NWAVE + lane]; tv.be = totW[1 * NWAVE + lane];
        tv.ga = totW[2 * NWAVE + lane]; tv.de = totW[3 * NWAVE + lane];
        tv.c  = totW[4 * NWAVE + lane]; tv.e  = totW[5 * NWAVE + lane];
        tv.f  = totW[6 * NWAVE + lane];
    }
    #pragma unroll
    for (int d = 1; d < NWAVE; d <<= 1) {
        DMat o = dmat_shfl_up(tv, d);
        if (lane >= d && lane < NWAVE) tv = dmat_compose(tv, o);
    }
    dmat_normalize(tv);

    // publish block-inclusive aggregate + set our ready bit (no waiting first)
    if (tid == NWAVE - 1) {                  // wave 0, lane 7 holds scanned[7]
        dmat_store_agent(L + bid * 7, tv);
        __threadfence();                     // L[bid] visible before the bit
        __hip_atomic_fetch_or(&words[bid >> 5], 1u << (bid & 31),
                              __ATOMIC_RELEASE, __HIP_MEMORY_SCOPE_AGENT);
    }

    // wave-exclusive prefix within block; thread-exclusive within block
    DMat Et;
    if (wid == 0) {
        Et = (lane == 0) ? dmat_identity() : laneExcl;
    } else {
        DMat waveExcl = dmat_shfl_bcast(tv, wid - 1);
        Et = (lane == 0) ? waveExcl : dmat_compose(laneExcl, waveExcl);
    }

    // ---- lookback wait: ONLY lanes 0..15 of wave 0 spin on the bitset ----
    // Bits needed: all tickets < bid. Only waits on SMALLER tickets ->
    // deadlock-free at any occupancy (they started earlier, never wait on us).
    if (wid == 0 && lane < NWORD) {
        const int hi = bid >> 5;
        unsigned int need = (lane < hi) ? 0xFFFFFFFFu
                          : (lane == hi ? ((1u << (bid & 31)) - 1u) : 0u);
        while ((__hip_atomic_load(&words[lane], __ATOMIC_ACQUIRE,
                                  __HIP_MEMORY_SCOPE_AGENT) & need) != need) {
            __builtin_amdgcn_s_sleep(1);
        }
    }
    __syncthreads();

    // ---- spine: ordered product of L[0..bid-1] (identity-padded >= bid) ----
    {
        DMat sv = dmat_identity();
        if (tid < bid) sv = dmat_load_agent(L + tid * 7);
        sv = dmat_wave_scan64(sv, lane);     // lane 63 = this wave's total
        if (lane == 63) {
            dmat_normalize(sv);
            totW[0 * NWAVE + wid] = sv.al; totW[1 * NWAVE + wid] = sv.be;
            totW[2 * NWAVE + wid] = sv.ga; totW[3 * NWAVE + wid] = sv.de;
            totW[4 * NWAVE + wid] = sv.c;  totW[5 * NWAVE + wid] = sv.e;
            totW[6 * NWAVE + wid] = sv.f;
        }
    }
    __syncthreads();

    // Eb = totW[7] ∘ totW[6] ∘ ... ∘ totW[0] (uniform; LDS broadcast reads)
    DMat Eb = dmat_identity();
    #pragma unroll
    for (int w = 0; w < NWAVE; ++w) {
        DMat T;
        T.al = totW[0 * NWAVE + w]; T.be = totW[1 * NWAVE + w];
        T.ga = totW[2 * NWAVE + w]; T.de = totW[3 * NWAVE + w];
        T.c  = totW[4 * NWAVE + w]; T.e  = totW[5 * NWAVE + w];
        T.f  = totW[6 * NWAVE + w];
        Eb = dmat_compose(T, Eb);            // later waves on the LEFT
    }
    dmat_normalize(Eb);

    // full-history exclusive composite for this thread
    DMat F = dmat_compose(Et, Eb);
    dmat_normalize(F);
    // apply at (x,g) = (0,0); x=0 is far from the repelling fixed point (~1)
    double x = 0.0, g = 0.0;
    if (F.de != 0.0 && !isinf(F.de)) {
        double invde = 1.0 / F.de;
        x = F.be * invde;
        g = F.f  * invde;
    }
    if (!isfinite(x)) x = 0.0;
    if (!isfinite(g)) g = 0.0;

    // ---- phase 3: replay from registers (u,U,V recomputed from bpack) ----
    double s_quad = 0.0, pd = 1.0;
    #pragma unroll
    for (int k = 0; k < NC; ++k) {
        int b = (int)((bpack >> (2 * k)) & 3u);
        double V = band_amp(b, amp1, amp2, amp3);
        double U = sigma2 * V;
        double P = (double)Pv[k], a = (double)av[k], yy = (double)yvv[k];
        double p = P * P;
        double S = p * x;
        double D = a - U * U * S;
        if (!(D > 1e-300)) D = 1e-300;  // NaN-proof; never triggers if math is right
        double invD = 1.0 / D;
        double W = (V - S * U) * invD;
        double gn = P * g;
        double z = yy - U * gn;
        pd *= D;
        s_quad = fma(z * z, invD, s_quad);
        x = fma(D * W, W, S);
        g = fma(W, z, gn);
    }
    double s_logD = log(pd);   // product of 8 O(1) D's: comfortably in range

    // wave reduce, then cross-wave step
    #pragma unroll
    for (int off = 32; off > 0; off >>= 1) {
        s_logD += __shfl_down(s_logD, off);
        s_quad += __shfl_down(s_quad, off);
    }
    if (lane == 0) { red[wid] = s_logD; red[NWAVE + wid] = s_quad; }
    __syncthreads();
    if (tid == 0) {
        double l = 0.0, q = 0.0;
        #pragma unroll
        for (int w = 0; w < NWAVE; ++w) { l += red[w]; q += red[NWAVE + w]; }
        atomicAdd(&accum[0], l);
        atomicAdd(&accum[1], q);
        __threadfence();
        unsigned int old = atomicAdd(done, 1u);
        if (old == NB - 1) {   // last block: finalize (atomic RMW reads = coherent)
            double LL = atomicAdd(&accum[0], 0.0);
            double QQ = atomicAdd(&accum[1], 0.0);
            out[0] = (float)(-0.5 * (QQ + LL
                     + (double)N_TOTAL * 1.8378770664093454836));  // log(2*pi)
        }
    }
}

extern "C" void kernel_launch(void* const* d_in, const int* in_sizes, int n_in,
                              void* d_out, int out_size, void* d_ws, size_t ws_size,
                              hipStream_t stream)
{
    const float* t    = (const float*)d_in[0];
    const int*   band = (const int*)d_in[1];
    const float* y    = (const float*)d_in[2];
    const float* yerr = (const float*)d_in[3];
    const float* lad  = (const float*)d_in[4];
    const float* lkp  = (const float*)d_in[5];

    double* dws          = (double*)d_ws;
    double* accum        = dws;                        // 2 doubles
    unsigned int* ctrs   = (unsigned int*)(dws + 2);   // ticket, done, words[16]
    unsigned int* ticket = ctrs;
    unsigned int* done   = ctrs + 1;
    unsigned int* words  = ctrs + 2;                   // 16 u32 bitset
    // ctrs region = 18 u32 = 72 B -> 9 doubles
    double* L            = dws + 2 + 9;                // NB * 7 doubles (28 KB)

    // zero accum + ticket + done + bitset (workspace is poisoned between runs)
    hipMemsetAsync(dws, 0, (2 + 9) * 8, stream);
    k_fused<<<NB, NT, 0, stream>>>(t, band, y, yerr, lad, lkp,
                                   L, accum, ticket, done, words, (float*)d_out);
}

// Round 11
// 119.393 us; speedup vs baseline: 1.4133x; 1.4133x over previous
//
#include <hip/hip_runtime.h>
#include <math.h>

// Problem constants (fixed by setup_inputs)
#define N_TOTAL 2097152
#define NT 512              // threads per block (8 waves)
#define NC 16               // elements per thread
#define EPB (NT * NC)       // 8192 elements per block
#define NB (N_TOTAL / EPB)  // 256 blocks == #CUs -> 1 block/CU, always co-resident
#define NWAVE (NT / 64)     // 8 waves per block

// Projective map on homogeneous (x, g, 1):
//   x' = (al*x + be) / (ga*x + de)
//   g' = (e*x + c*g + f) / (ga*x + de)
// Matrix [[al,0,be],[e,c,f],[ga,0,de]] — closed under composition.
// Compose algebra in DOUBLE; per-element decay P in fp32 (matches the fp32
// reference: fp32 diff of adjacent sorted t is exact, expf ~1 ulp).
struct DMat { double al, be, ga, de, c, e, f; };

__device__ __forceinline__ DMat dmat_identity() {
    DMat m; m.al = 1.0; m.be = 0.0; m.ga = 0.0; m.de = 1.0; m.c = 1.0; m.e = 0.0; m.f = 0.0;
    return m;
}

// A applied AFTER B (matrix product A*B)
__device__ __forceinline__ DMat dmat_compose(const DMat& A, const DMat& B) {
    DMat r;
    r.al = A.al * B.al + A.be * B.ga;
    r.be = A.al * B.be + A.be * B.de;
    r.ga = A.ga * B.al + A.de * B.ga;
    r.de = A.ga * B.be + A.de * B.de;
    r.c  = A.c * B.c;
    r.e  = A.e * B.al + A.c * B.e + A.f * B.ga;
    r.f  = A.e * B.be + A.c * B.f + A.f * B.de;
    return r;
}

// Scale-invariant normalization. The scale factor needs NO precision (pure
// rescale), so use fp32 v_rcp when mx is in fp32 range (guarded), else the
// exact fp64 divide. Guarded so it can never manufacture NaN/Inf.
__device__ __forceinline__ void dmat_normalize(DMat& m) {
    double mx = fmax(fabs(m.al), fabs(m.be));
    mx = fmax(mx, fabs(m.ga));
    mx = fmax(mx, fabs(m.de));
    mx = fmax(mx, fabs(m.c));
    mx = fmax(mx, fabs(m.e));
    mx = fmax(mx, fabs(m.f));
    if (!(mx > 0.0) || isinf(mx)) return;   // all-zero or corrupt: leave as-is
    float mf = (float)mx;
    double inv = (mf > 1e-30f && mf < 1e30f)
               ? (double)(1.0f / mf)        // fp32 rcp path (~1 ulp, fine for a scale)
               : 1.0 / mx;
    m.al *= inv; m.be *= inv; m.ga *= inv; m.de *= inv;
    m.c *= inv; m.e *= inv; m.f *= inv;
}

__device__ __forceinline__ DMat dmat_shfl_up(const DMat& m, int d) {
    DMat r;
    r.al = __shfl_up(m.al, d); r.be = __shfl_up(m.be, d);
    r.ga = __shfl_up(m.ga, d); r.de = __shfl_up(m.de, d);
    r.c  = __shfl_up(m.c,  d); r.e  = __shfl_up(m.e,  d);
    r.f  = __shfl_up(m.f,  d);
    return r;
}

__device__ __forceinline__ DMat dmat_shfl_bcast(const DMat& m, int src) {
    DMat r;
    r.al = __shfl(m.al, src); r.be = __shfl(m.be, src);
    r.ga = __shfl(m.ga, src); r.de = __shfl(m.de, src);
    r.c  = __shfl(m.c,  src); r.e  = __shfl(m.e,  src);
    r.f  = __shfl(m.f,  src);
    return r;
}

// Barrier-free inclusive scan across the 64 lanes of a wave.
__device__ __forceinline__ DMat dmat_wave_scan64(DMat mine, int lane) {
    #pragma unroll
    for (int d = 1; d < 64; d <<= 1) {
        DMat o = dmat_shfl_up(mine, d);
        if (lane >= d) mine = dmat_compose(mine, o);
    }
    return mine;
}

__device__ __forceinline__ DMat elem_mat(double P, double a, double U, double V, double yy) {
    double p = P * P;
    DMat m;
    m.al = p * (a - 2.0 * U * V);
    m.be = V * V;
    m.ga = -(p * U * U);
    m.de = a;
    m.c  = P * (a - U * V);
    m.e  = -(yy * p * U);
    m.f  = yy * V;
    return m;
}

// Register-resident 4-way select (avoid runtime-indexed array -> scratch).
__device__ __forceinline__ double band_amp(int b, double a1, double a2, double a3) {
    double lo = (b & 1) ? a1 : 1.0;
    double hi = (b & 1) ? a3 : a2;
    return (b & 2) ? hi : lo;
}

// Device-coherent (agent-scope) matrix store/load for cross-block handoff.
// PROVEN-CORRECT PATH (rounds 5/8/9): do not replace with plain cached loads
// — per-CU L1 / per-XCD L2 can serve stale values (round-10 lesson).
__device__ __forceinline__ void dmat_store_agent(double* p, const DMat& m) {
    __hip_atomic_store(&p[0], m.al, __ATOMIC_RELAXED, __HIP_MEMORY_SCOPE_AGENT);
    __hip_atomic_store(&p[1], m.be, __ATOMIC_RELAXED, __HIP_MEMORY_SCOPE_AGENT);
    __hip_atomic_store(&p[2], m.ga, __ATOMIC_RELAXED, __HIP_MEMORY_SCOPE_AGENT);
    __hip_atomic_store(&p[3], m.de, __ATOMIC_RELAXED, __HIP_MEMORY_SCOPE_AGENT);
    __hip_atomic_store(&p[4], m.c,  __ATOMIC_RELAXED, __HIP_MEMORY_SCOPE_AGENT);
    __hip_atomic_store(&p[5], m.e,  __ATOMIC_RELAXED, __HIP_MEMORY_SCOPE_AGENT);
    __hip_atomic_store(&p[6], m.f,  __ATOMIC_RELAXED, __HIP_MEMORY_SCOPE_AGENT);
}

__device__ __forceinline__ DMat dmat_load_agent(const double* p) {
    DMat m;
    m.al = __hip_atomic_load(&p[0], __ATOMIC_RELAXED, __HIP_MEMORY_SCOPE_AGENT);
    m.be = __hip_atomic_load(&p[1], __ATOMIC_RELAXED, __HIP_MEMORY_SCOPE_AGENT);
    m.ga = __hip_atomic_load(&p[2], __ATOMIC_RELAXED, __HIP_MEMORY_SCOPE_AGENT);
    m.de = __hip_atomic_load(&p[3], __ATOMIC_RELAXED, __HIP_MEMORY_SCOPE_AGENT);
    m.c  = __hip_atomic_load(&p[4], __ATOMIC_RELAXED, __HIP_MEMORY_SCOPE_AGENT);
    m.e  = __hip_atomic_load(&p[5], __ATOMIC_RELAXED, __HIP_MEMORY_SCOPE_AGENT);
    m.f  = __hip_atomic_load(&p[6], __ATOMIC_RELAXED, __HIP_MEMORY_SCOPE_AGENT);
    return m;
}

// ------------------------- single fused kernel ---------------------------
// R5 structure (best measured: 51 us) + the SAFE subset of R10's changes:
//  - all 16 input vectors loaded up-front (max memory-level parallelism)
//  - t[base-1] via __shfl_up: 8 scalar loads/block instead of 512
//  - LDS-light identity-padded spine (R9 scheme): 448 B totW, no 14 KB spI
//  - normalize uses guarded fp32 rcp instead of fp64 divide
//  - spine reads: PROVEN agent-scope atomic loads (R10's plain-cached-load
//    experiment coincided with a container failure; reverted)
// Grid barrier: NB=256 = 1 block/CU -> co-residency unconditional (safe).
__global__ __launch_bounds__(NT, 2) void k_fused(
    const float* __restrict__ t, const int* __restrict__ band,
    const float* __restrict__ y, const float* __restrict__ yerr,
    const float* __restrict__ lad, const float* __restrict__ lkp,
    double* __restrict__ L, double* __restrict__ accum,
    unsigned int* __restrict__ bar0, unsigned int* __restrict__ done,
    float* __restrict__ out)
{
    __shared__ double totW[7 * NWAVE];   // 8 wave totals (reused by spine)
    __shared__ double red[2 * NWAVE];

    const int tid  = threadIdx.x;
    const int lane = tid & 63;
    const int wid  = tid >> 6;
    const int bid  = blockIdx.x;

    const double sigma2 = exp(2.0 * (double)lkp[0]);
    const float inv_ell_f = expf(-lkp[1]);
    const double amp1 = exp((double)lad[0]);
    const double amp2 = exp((double)lad[1]);
    const double amp3 = exp((double)lad[2]);

    const int gid  = bid * NT + tid;
    const int base = gid * NC;
    const bool first = (gid == 0);

    // ---- ALL input loads issued up front (16 vector loads / thread) ----
    float4 T4[4], Y4[4], E4[4]; int4 B4[4];
    #pragma unroll
    for (int q = 0; q < 4; ++q) {
        T4[q] = *reinterpret_cast<const float4*>(t    + base + 4 * q);
        Y4[q] = *reinterpret_cast<const float4*>(y    + base + 4 * q);
        E4[q] = *reinterpret_cast<const float4*>(yerr + base + 4 * q);
        B4[q] = *reinterpret_cast<const int4*>(band + base + 4 * q);
    }
    // previous-element time: from the neighbor lane's last element
    float lastT = T4[3].w;                        // t[base+15]
    float prevLast = __shfl_up(lastT, 1);
    float tpA = (lane > 0) ? prevLast
              : (first ? 0.0f : t[base - 1]);     // 8 scalar loads/block
    float tpB = T4[1].w;                          // t[base+7]

    // replay state: 3x16 fp32 + 1 packed-band u32 = 49 VGPRs
    float Pv[NC], av[NC], yvv[NC];
    unsigned int bpack = 0;

    // ---- phase 1: two independent 8-element chains (2x ILP) ----
    DMat accA = dmat_identity();
    DMat accB = dmat_identity();
    #pragma unroll
    for (int q = 0; q < 2; ++q) {
        float tA[4] = {T4[q].x, T4[q].y, T4[q].z, T4[q].w};
        float yA[4] = {Y4[q].x, Y4[q].y, Y4[q].z, Y4[q].w};
        float eA[4] = {E4[q].x, E4[q].y, E4[q].z, E4[q].w};
        int   bA[4] = {B4[q].x, B4[q].y, B4[q].z, B4[q].w};
        float tB[4] = {T4[q+2].x, T4[q+2].y, T4[q+2].z, T4[q+2].w};
        float yB[4] = {Y4[q+2].x, Y4[q+2].y, Y4[q+2].z, Y4[q+2].w};
        float eB[4] = {E4[q+2].x, E4[q+2].y, E4[q+2].z, E4[q+2].w};
        int   bB[4] = {B4[q+2].x, B4[q+2].y, B4[q+2].z, B4[q+2].w};
        #pragma unroll
        for (int j = 0; j < 4; ++j) {
            {   // chain A: elements [0, 8)
                int ix = 4 * q + j;
                int b = bA[j] & 3;
                bpack |= (unsigned int)b << (2 * ix);
                double u = band_amp(b, amp1, amp2, amp3);
                double U = sigma2 * u;
                double a = (double)eA[j] * (double)eA[j] + U * u;
                float dt = tA[j] - tpA; tpA = tA[j];
                float pf = (first && ix == 0) ? 0.0f : expf(-dt * inv_ell_f);
                Pv[ix] = pf; av[ix] = (float)a; yvv[ix] = yA[j];
                accA = dmat_compose(elem_mat((double)pf, a, U, u, (double)yA[j]), accA);
            }
            {   // chain B: elements [8, 16) — independent of chain A
                int ix = 8 + 4 * q + j;
                int b = bB[j] & 3;
                bpack |= (unsigned int)b << (2 * ix);
                double u = band_amp(b, amp1, amp2, amp3);
                double U = sigma2 * u;
                double a = (double)eB[j] * (double)eB[j] + U * u;
                float dt = tB[j] - tpB; tpB = tB[j];
                float pf = expf(-dt * inv_ell_f);
                Pv[ix] = pf; av[ix] = (float)a; yvv[ix] = yB[j];
                accB = dmat_compose(elem_mat((double)pf, a, U, u, (double)yB[j]), accB);
            }
        }
    }
    DMat acc = dmat_compose(accB, accA);
    dmat_normalize(acc);

    // ---- barrier-free wave scan; 1 LDS step for the 8 wave totals ----
    DMat incl = dmat_wave_scan64(acc, lane);
    dmat_normalize(incl);
    DMat laneExcl = dmat_shfl_up(incl, 1);   // lane 0: garbage (handled below)
    if (lane == 63) {                        // publish wave total
        totW[0 * NWAVE + wid] = incl.al; totW[1 * NWAVE + wid] = incl.be;
        totW[2 * NWAVE + wid] = incl.ga; totW[3 * NWAVE + wid] = incl.de;
        totW[4 * NWAVE + wid] = incl.c;  totW[5 * NWAVE + wid] = incl.e;
        totW[6 * NWAVE + wid] = incl.f;
    }
    __syncthreads();

    // redundant 8-element shuffle scan of wave totals (every wave; no barrier)
    DMat tv = dmat_identity();
    if (lane < NWAVE) {
        tv.al = totW[0 * NWAVE + lane]; tv.be = totW[1 * NWAVE + lane];
        tv.ga = totW[2 * NWAVE + lane]; tv.de = totW[3 * NWAVE + lane];
        tv.c  = totW[4 * NWAVE + lane]; tv.e  = totW[5 * NWAVE + lane];
        tv.f  = totW[6 * NWAVE + lane];
    }
    #pragma unroll
    for (int d = 1; d < NWAVE; d <<= 1) {
        DMat o = dmat_shfl_up(tv, d);
        if (lane >= d && lane < NWAVE) tv = dmat_compose(tv, o);
    }
    dmat_normalize(tv);

    // publish block-inclusive composite (scanned[7] lives in lane 7, wave 0)
    if (tid == NWAVE - 1) {
        dmat_store_agent(L + bid * 7, tv);
    }

    // wave-exclusive prefix within block; thread-exclusive within block
    DMat Et;
    if (wid == 0) {
        Et = (lane == 0) ? dmat_identity() : laneExcl;
    } else {
        DMat waveExcl = dmat_shfl_bcast(tv, wid - 1);
        Et = (lane == 0) ? waveExcl : dmat_compose(laneExcl, waveExcl);
    }

    // ---- grid barrier (1 block/CU: co-residency unconditional) ----
    __syncthreads();                 // drains the L agent-stores (vmcnt) too
    if (tid == 0) {
        __threadfence();             // release: L[bid] visible device-wide
        atomicAdd(bar0, 1u);
        while (__hip_atomic_load(bar0, __ATOMIC_ACQUIRE,
                                 __HIP_MEMORY_SCOPE_AGENT) < NB) {
            __builtin_amdgcn_s_sleep(2);
        }
    }
    __syncthreads();

    // ---- spine: ordered product of L[0..bid-1], identity-padded >= bid ----
    // 4 waves x 64 = 256 entries; agent-scope atomic loads (proven path).
    if (wid < 4) {
        DMat sv = dmat_identity();
        if (tid < bid) sv = dmat_load_agent(L + tid * 7);
        sv = dmat_wave_scan64(sv, lane);     // lane 63 = this wave's total
        if (lane == 63) {
            dmat_normalize(sv);
            totW[0 * NWAVE + wid] = sv.al; totW[1 * NWAVE + wid] = sv.be;
            totW[2 * NWAVE + wid] = sv.ga; totW[3 * NWAVE + wid] = sv.de;
            totW[4 * NWAVE + wid] = sv.c;  totW[5 * NWAVE + wid] = sv.e;
            totW[6 * NWAVE + wid] = sv.f;
        }
    }
    __syncthreads();

    // Eb = totW[3] ∘ totW[2] ∘ totW[1] ∘ totW[0]  (identity-padded beyond bid
    // means this equals the composite of blocks 0..bid-1 exactly)
    DMat Eb = dmat_identity();
    #pragma unroll
    for (int w = 0; w < 4; ++w) {
        DMat T;
        T.al = totW[0 * NWAVE + w]; T.be = totW[1 * NWAVE + w];
        T.ga = totW[2 * NWAVE + w]; T.de = totW[3 * NWAVE + w];
        T.c  = totW[4 * NWAVE + w]; T.e  = totW[5 * NWAVE + w];
        T.f  = totW[6 * NWAVE + w];
        Eb = dmat_compose(T, Eb);            // later waves on the LEFT
    }
    dmat_normalize(Eb);

    // full-history exclusive composite for this thread
    DMat F = dmat_compose(Et, Eb);
    dmat_normalize(F);
    // apply at (x,g) = (0,0); x=0 is far from the repelling fixed point (~1)
    double x = 0.0, g = 0.0;
    if (F.de != 0.0 && !isinf(F.de)) {
        double invde = 1.0 / F.de;
        x = F.be * invde;
        g = F.f  * invde;
    }
    if (!isfinite(x)) x = 0.0;
    if (!isfinite(g)) g = 0.0;

    // ---- phase 3: replay from registers (u,U,V recomputed from bpack) ----
    double s_logD = 0.0, s_quad = 0.0, pd = 1.0;
    #pragma unroll
    for (int k = 0; k < NC; ++k) {
        int b = (int)((bpack >> (2 * k)) & 3u);
        double V = band_amp(b, amp1, amp2, amp3);
        double U = sigma2 * V;
        double P = (double)Pv[k], a = (double)av[k], yy = (double)yvv[k];
        double p = P * P;
        double S = p * x;
        double D = a - U * U * S;
        if (!(D > 1e-300)) D = 1e-300;  // NaN-proof; never triggers if math is right
        double invD = 1.0 / D;
        double W = (V - S * U) * invD;
        double gn = P * g;
        double z = yy - U * gn;
        pd *= D;
        s_quad = fma(z * z, invD, s_quad);
        x = fma(D * W, W, S);
        g = fma(W, z, gn);
        if ((k & 7) == 7) {            // fold product every 8 elements
            s_logD += log(pd);
            pd = 1.0;
        }
    }

    // wave reduce, then cross-wave step
    #pragma unroll
    for (int off = 32; off > 0; off >>= 1) {
        s_logD += __shfl_down(s_logD, off);
        s_quad += __shfl_down(s_quad, off);
    }
    if (lane == 0) { red[wid] = s_logD; red[NWAVE + wid] = s_quad; }
    __syncthreads();
    if (tid == 0) {
        double l = 0.0, q = 0.0;
        #pragma unroll
        for (int w = 0; w < NWAVE; ++w) { l += red[w]; q += red[NWAVE + w]; }
        atomicAdd(&accum[0], l);
        atomicAdd(&accum[1], q);
        __threadfence();
        unsigned int old = atomicAdd(done, 1u);
        if (old == NB - 1) {   // last block: finalize (atomic RMW reads = coherent)
            double LL = atomicAdd(&accum[0], 0.0);
            double QQ = atomicAdd(&accum[1], 0.0);
            out[0] = (float)(-0.5 * (QQ + LL
                     + (double)N_TOTAL * 1.8378770664093454836));  // log(2*pi)
        }
    }
}

extern "C" void kernel_launch(void* const* d_in, const int* in_sizes, int n_in,
                              void* d_out, int out_size, void* d_ws, size_t ws_size,
                              hipStream_t stream)
{
    const float* t    = (const float*)d_in[0];
    const int*   band = (const int*)d_in[1];
    const float* y    = (const float*)d_in[2];
    const float* yerr = (const float*)d_in[3];
    const float* lad  = (const float*)d_in[4];
    const float* lkp  = (const float*)d_in[5];

    double* dws        = (double*)d_ws;
    double* accum      = dws;                         // 2 doubles
    unsigned int* ctrs = (unsigned int*)(dws + 2);    // bar0, done
    double* L          = dws + 4;                     // NB * 7 doubles (14 KB)

    // zero accum + control words (workspace is poisoned between iterations)
    hipMemsetAsync(dws, 0, 32, stream);
    k_fused<<<NB, NT, 0, stream>>>(t, band, y, yerr, lad, lkp,
                                   L, accum, ctrs, ctrs + 1, (float*)d_out);
}